// Round 1
// baseline (1140.954 us; speedup 1.0000x reference)
//
#include <hip/hip_runtime.h>
#include <hip/hip_bf16.h>

// Problem constants (fixed by setup_inputs):
//   B=2, F=T=2048, D=1024, N=16 heads, H=64; out = context [B,F,N,H] f32
#define B_DIM   2
#define S_DIM   2048   // F == T
#define D_DIM   1024
#define N_HEADS 16
#define H_DIM   64
#define NH      1024   // N_HEADS * H_DIM

// ---------------------------------------------------------------------------
// Projection GEMM:  out[b][n][s][h] = sum_d X[b*S+s][d] * W[d][n*64+h] + bias
// X: [B*S, D] row-major, W: [D, NH] row-major, bias: [NH]
// out stored as [B][N][S][H] so the attention kernel reads contiguous rows.
// Tile 64x64, K-tile 16, 256 threads, 4x4 microtile per thread. All f32.
// ---------------------------------------------------------------------------
__global__ __launch_bounds__(256)
void proj_kernel(const float* __restrict__ X, const float* __restrict__ W,
                 const float* __restrict__ bias, float* __restrict__ out)
{
    // pad 68 floats: row byte-stride 272 (16B-aligned for b128, odd bank-quad)
    __shared__ float As[16][68];   // As[k][m] (transposed A tile)
    __shared__ float Bs[16][68];   // Bs[k][n]

    const int tid = threadIdx.x;
    const int tx = tid & 15, ty = tid >> 4;
    const int row0 = blockIdx.x * 64;   // M = B*S = 4096 -> 64 blocks
    const int col0 = blockIdx.y * 64;   // NH = 1024     -> 16 blocks

    const int lk  = tid & 15;    // A-load: k index
    const int lm  = tid >> 4;    // A-load: m base
    const int lnB = tid & 63;    // B-load: n index
    const int lkB = tid >> 6;    // B-load: k base

    float acc[4][4] = {};

    for (int k0 = 0; k0 < D_DIM; k0 += 16) {
        #pragma unroll
        for (int i = 0; i < 4; ++i)
            As[lk][lm + 16 * i] = X[(row0 + lm + 16 * i) * D_DIM + k0 + lk];
        #pragma unroll
        for (int i = 0; i < 4; ++i)
            Bs[lkB + 4 * i][lnB] = W[(k0 + lkB + 4 * i) * NH + col0 + lnB];
        __syncthreads();

        #pragma unroll
        for (int k = 0; k < 16; ++k) {
            float4 a4 = *(const float4*)&As[k][ty * 4];
            float4 b4 = *(const float4*)&Bs[k][tx * 4];
            float a[4] = {a4.x, a4.y, a4.z, a4.w};
            float b[4] = {b4.x, b4.y, b4.z, b4.w};
            #pragma unroll
            for (int i = 0; i < 4; ++i)
                #pragma unroll
                for (int j = 0; j < 4; ++j)
                    acc[i][j] = fmaf(a[i], b[j], acc[i][j]);
        }
        __syncthreads();
    }

    // Epilogue: cols are one head (col0 aligned to 64) -> n fixed per block.
    const int n = col0 >> 6;
    #pragma unroll
    for (int i = 0; i < 4; ++i) {
        const int r = row0 + ty * 4 + i;   // global row in [0, B*S)
        const int b = r >> 11;             // / 2048
        const int s = r & 2047;
        float4 v;
        v.x = acc[i][0] + bias[col0 + tx * 4 + 0];
        v.y = acc[i][1] + bias[col0 + tx * 4 + 1];
        v.z = acc[i][2] + bias[col0 + tx * 4 + 2];
        v.w = acc[i][3] + bias[col0 + tx * 4 + 3];
        *(float4*)&out[(((size_t)(b * N_HEADS + n) * S_DIM) + s) * H_DIM + tx * 4] = v;
    }
}

// ---------------------------------------------------------------------------
// Fused flash-style attention (all f32, online softmax in registers).
// Grid: (F/64, N, B); 256 threads.
// Per block: 64 Q rows for one (b, n). Stream K/V in 64-row tiles.
// Thread (tx,ty): rows f = ty + 16*i, score-cols t = tx + 16*j,
//                 context-cols h = tx + 16*j.  Row reductions via shfl
//                 (each row's 16 owners are the 16 tx lanes of one wave).
// ---------------------------------------------------------------------------
__global__ __launch_bounds__(256)
void attn_kernel(const float* __restrict__ Qw, const float* __restrict__ Kw,
                 const float* __restrict__ Vw, const int* __restrict__ mask,
                 float* __restrict__ out)
{
    __shared__ float Qs[64][68];
    __shared__ float Ks[64][68];
    __shared__ float Vs[64][68];
    __shared__ float Ss[64][68];

    const int tid = threadIdx.x;
    const int tx = tid & 15, ty = tid >> 4;
    const int f0 = blockIdx.x * 64;
    const int n  = blockIdx.y;
    const int b  = blockIdx.z;

    const float* Qb = Qw + (size_t)(b * N_HEADS + n) * S_DIM * H_DIM;
    const float* Kb = Kw + (size_t)(b * N_HEADS + n) * S_DIM * H_DIM;
    const float* Vb = Vw + (size_t)(b * N_HEADS + n) * S_DIM * H_DIM;
    const int*   mb = mask + (size_t)(b * S_DIM + f0) * S_DIM;

    const int lh4 = (tid & 15) * 4;   // h chunk for tile loads
    const int lr  = tid >> 4;         // row base for tile loads

    // Load Q tile once.
    #pragma unroll
    for (int i = 0; i < 4; ++i)
        *(float4*)&Qs[lr + 16 * i][lh4] =
            *(const float4*)&Qb[(size_t)(f0 + lr + 16 * i) * H_DIM + lh4];

    float acc[4][4] = {};
    float mrow[4] = {-1e30f, -1e30f, -1e30f, -1e30f};
    float lrow[4] = {0.f, 0.f, 0.f, 0.f};

    for (int t0 = 0; t0 < S_DIM; t0 += 64) {
        // Load K, V tiles.
        #pragma unroll
        for (int i = 0; i < 4; ++i) {
            *(float4*)&Ks[lr + 16 * i][lh4] =
                *(const float4*)&Kb[(size_t)(t0 + lr + 16 * i) * H_DIM + lh4];
            *(float4*)&Vs[lr + 16 * i][lh4] =
                *(const float4*)&Vb[(size_t)(t0 + lr + 16 * i) * H_DIM + lh4];
        }
        __syncthreads();

        // S = Q K^T  (64x64 scores, 4x4 per thread)
        float s[4][4] = {};
        #pragma unroll
        for (int h0 = 0; h0 < H_DIM; h0 += 4) {
            float4 q4[4], k4[4];
            #pragma unroll
            for (int i = 0; i < 4; ++i) q4[i] = *(const float4*)&Qs[ty + 16 * i][h0];
            #pragma unroll
            for (int j = 0; j < 4; ++j) k4[j] = *(const float4*)&Ks[tx + 16 * j][h0];
            #pragma unroll
            for (int i = 0; i < 4; ++i)
                #pragma unroll
                for (int j = 0; j < 4; ++j) {
                    s[i][j] = fmaf(q4[i].x, k4[j].x, s[i][j]);
                    s[i][j] = fmaf(q4[i].y, k4[j].y, s[i][j]);
                    s[i][j] = fmaf(q4[i].z, k4[j].z, s[i][j]);
                    s[i][j] = fmaf(q4[i].w, k4[j].w, s[i][j]);
                }
        }

        // scale + mask adder: (1 - mask) * -10000
        #pragma unroll
        for (int i = 0; i < 4; ++i) {
            const int* mrp = &mb[(size_t)(ty + 16 * i) * S_DIM + t0];
            #pragma unroll
            for (int j = 0; j < 4; ++j) {
                float sv = s[i][j] * 0.125f;               // 1/sqrt(64)
                sv += (1.0f - (float)mrp[tx + 16 * j]) * -10000.0f;
                s[i][j] = sv;
            }
        }

        // Online softmax: row reduction across the 16 tx lanes (same wave).
        #pragma unroll
        for (int i = 0; i < 4; ++i) {
            float mx = fmaxf(fmaxf(s[i][0], s[i][1]), fmaxf(s[i][2], s[i][3]));
            #pragma unroll
            for (int off = 1; off < 16; off <<= 1)
                mx = fmaxf(mx, __shfl_xor(mx, off, 64));
            const float mnew = fmaxf(mrow[i], mx);
            const float c = __expf(mrow[i] - mnew);
            mrow[i] = mnew;
            float ps = 0.f;
            #pragma unroll
            for (int j = 0; j < 4; ++j) {
                s[i][j] = __expf(s[i][j] - mnew);
                ps += s[i][j];
            }
            #pragma unroll
            for (int off = 1; off < 16; off <<= 1)
                ps += __shfl_xor(ps, off, 64);
            lrow[i] = lrow[i] * c + ps;
            #pragma unroll
            for (int j = 0; j < 4; ++j) acc[i][j] *= c;
        }

        // Stage P for the PV product.
        #pragma unroll
        for (int i = 0; i < 4; ++i)
            #pragma unroll
            for (int j = 0; j < 4; ++j)
                Ss[ty + 16 * i][tx + 16 * j] = s[i][j];
        __syncthreads();

        // acc += P @ V  (k over 64 t-positions, 4 at a time via float4 P reads)
        #pragma unroll
        for (int kk = 0; kk < 64; kk += 4) {
            float p[4][4];
            #pragma unroll
            for (int i = 0; i < 4; ++i) {
                float4 p4 = *(const float4*)&Ss[ty + 16 * i][kk];
                p[i][0] = p4.x; p[i][1] = p4.y; p[i][2] = p4.z; p[i][3] = p4.w;
            }
            #pragma unroll
            for (int u = 0; u < 4; ++u) {
                float v[4];
                #pragma unroll
                for (int j = 0; j < 4; ++j) v[j] = Vs[kk + u][tx + 16 * j];
                #pragma unroll
                for (int i = 0; i < 4; ++i)
                    #pragma unroll
                    for (int j = 0; j < 4; ++j)
                        acc[i][j] = fmaf(p[i][u], v[j], acc[i][j]);
            }
        }
        __syncthreads();
    }

    // Epilogue: out[b][f][n][h] = acc / l
    #pragma unroll
    for (int i = 0; i < 4; ++i) {
        const float inv = 1.0f / lrow[i];
        const int f = f0 + ty + 16 * i;
        #pragma unroll
        for (int j = 0; j < 4; ++j)
            out[((size_t)(b * S_DIM + f) * N_HEADS + n) * H_DIM + tx + 16 * j] =
                acc[i][j] * inv;
    }
}

extern "C" void kernel_launch(void* const* d_in, const int* in_sizes, int n_in,
                              void* d_out, int out_size, void* d_ws, size_t ws_size,
                              hipStream_t stream)
{
    const float* from = (const float*)d_in[0];   // [B,F,D]
    const float* to   = (const float*)d_in[1];   // [B,T,D]
    const int*   mask = (const int*)d_in[2];     // [B,F,T]
    const float* wq   = (const float*)d_in[3];
    const float* bq   = (const float*)d_in[4];
    const float* wk   = (const float*)d_in[5];
    const float* bk   = (const float*)d_in[6];
    const float* wv   = (const float*)d_in[7];
    const float* bv   = (const float*)d_in[8];
    float* out = (float*)d_out;

    const size_t qkv_elems = (size_t)B_DIM * N_HEADS * S_DIM * H_DIM; // 4 Mi
    float* Qw = (float*)d_ws;
    float* Kw = Qw + qkv_elems;
    float* Vw = Kw + qkv_elems;
    // needs 3 * 16.78 MB = 50.3 MB of workspace

    dim3 pgrid((B_DIM * S_DIM) / 64, NH / 64);   // (64, 16)
    proj_kernel<<<pgrid, 256, 0, stream>>>(from, wq, bq, Qw);
    proj_kernel<<<pgrid, 256, 0, stream>>>(to,   wk, bk, Kw);
    proj_kernel<<<pgrid, 256, 0, stream>>>(to,   wv, bv, Vw);

    dim3 agrid(S_DIM / 64, N_HEADS, B_DIM);      // (32, 16, 2)
    attn_kernel<<<agrid, 256, 0, stream>>>(Qw, Kw, Vw, mask, out);
}

// Round 2
// 267.499 us; speedup vs baseline: 4.2653x; 4.2653x over previous
//
#include <hip/hip_runtime.h>

#define B_DIM   2
#define S_DIM   2048
#define D_DIM   1024
#define N_HEADS 16
#define H_DIM   64
#define NH      1024
#define M_DIM   4096   // B * S

typedef short bf16x8 __attribute__((ext_vector_type(8)));
typedef short bf16x4 __attribute__((ext_vector_type(4)));
typedef float f32x4  __attribute__((ext_vector_type(4)));

__device__ __forceinline__ short f2bf(float x) {
    unsigned u = __float_as_uint(x);
    u = (u + 0x7fffu + ((u >> 16) & 1u)) >> 16;   // round-nearest-even
    return (short)u;
}

// ---------------------------------------------------------------------------
// f32 -> bf16 flat convert (float4 in, bf16x4 out)
// ---------------------------------------------------------------------------
__global__ __launch_bounds__(256)
void cvt_bf16(const float* __restrict__ src, short* __restrict__ dst, int n4) {
    int i = blockIdx.x * blockDim.x + threadIdx.x;
    if (i >= n4) return;
    float4 v = ((const float4*)src)[i];
    bf16x4 o;
    o[0] = f2bf(v.x); o[1] = f2bf(v.y); o[2] = f2bf(v.z); o[3] = f2bf(v.w);
    ((bf16x4*)dst)[i] = o;
}

// ---------------------------------------------------------------------------
// W [1024 d][1024 nh] f32  ->  Wt [1024 nh][1024 d] bf16  (64x64 LDS tiles)
// LDS row stride 66 shorts (33 dwords, odd) -> ~2-way conflicts on scalars.
// ---------------------------------------------------------------------------
__global__ __launch_bounds__(256)
void wtrans(const float* __restrict__ W, short* __restrict__ Wt) {
    __shared__ short T[64][66];   // T[n_local][d_local]
    const int d0 = blockIdx.x * 64, n0 = blockIdx.y * 64;
    const int tid = threadIdx.x;
    {
        const int dr = tid >> 2, nc = (tid & 3) * 16;
        const float* src = &W[(size_t)(d0 + dr) * NH + n0 + nc];
        float vv[16];
        #pragma unroll
        for (int q = 0; q < 4; ++q) {
            float4 v = ((const float4*)src)[q];
            vv[q*4+0] = v.x; vv[q*4+1] = v.y; vv[q*4+2] = v.z; vv[q*4+3] = v.w;
        }
        #pragma unroll
        for (int j = 0; j < 16; ++j) T[nc + j][dr] = f2bf(vv[j]);
    }
    __syncthreads();
    {
        const int nr = tid >> 2, dc = (tid & 3) * 16;
        short o[16];
        #pragma unroll
        for (int j = 0; j < 16; ++j) o[j] = T[nr][dc + j];
        short* dstp = &Wt[(size_t)(n0 + nr) * D_DIM + d0 + dc];
        *(bf16x8*)(dstp)     = *(bf16x8*)&o[0];
        *(bf16x8*)(dstp + 8) = *(bf16x8*)&o[8];
    }
}

// ---------------------------------------------------------------------------
// mask int32 [B][F][T] -> packed bits u64 [B][F][T/64] (bit i = mask at t0+i)
// ---------------------------------------------------------------------------
__global__ __launch_bounds__(256)
void maskpack(const int* __restrict__ mask, unsigned long long* __restrict__ mp,
              int total) {
    const int lane = threadIdx.x & 63;
    const int wid  = (blockIdx.x * blockDim.x + threadIdx.x) >> 6;
    const int nw   = (gridDim.x * blockDim.x) >> 6;
    for (int idx = wid; idx < total; idx += nw) {
        int m = mask[(size_t)idx * 64 + lane];
        unsigned long long bits = __ballot(m != 0);
        if (lane == 0) mp[idx] = bits;
    }
}

// ---------------------------------------------------------------------------
// Projection: C[row][nh] = sum_d Xb[row][d] * Wt[nh][d] + bias[nh]
// 128x128 tile, BK=32, 4 waves (2x2 of 64x64), MFMA 16x16x32 bf16.
// mode 0/1: out bf16 [B][N][S][H];  mode 2: out bf16 [B][N][H][S] (transposed)
// ---------------------------------------------------------------------------
__global__ __launch_bounds__(256)
void proj_mfma(const short* __restrict__ Xb, const short* __restrict__ Wt,
               const float* __restrict__ bias, short* __restrict__ out, int mode)
{
    __shared__ short Al[128][40];
    __shared__ short Bl[128][40];
    __shared__ short Tb[4][16][20];

    const int tid  = threadIdx.x;
    const int lane = tid & 63, w = tid >> 6;
    const int g = lane >> 4, l15 = lane & 15;
    const int wm = w >> 1, wn = w & 1;
    const int row0 = blockIdx.x * 128, col0 = blockIdx.y * 128;
    const int sm = tid >> 1, sk = (tid & 1) * 16;

    f32x4 acc[4][4];
    #pragma unroll
    for (int i = 0; i < 4; ++i)
        #pragma unroll
        for (int j = 0; j < 4; ++j)
            acc[i][j] = (f32x4){0.f, 0.f, 0.f, 0.f};

    for (int k0 = 0; k0 < D_DIM; k0 += 32) {
        __syncthreads();
        const short* ap = &Xb[(size_t)(row0 + sm) * D_DIM + k0 + sk];
        *(bf16x8*)&Al[sm][sk]     = *(const bf16x8*)ap;
        *(bf16x8*)&Al[sm][sk + 8] = *(const bf16x8*)(ap + 8);
        const short* bp = &Wt[(size_t)(col0 + sm) * D_DIM + k0 + sk];
        *(bf16x8*)&Bl[sm][sk]     = *(const bf16x8*)bp;
        *(bf16x8*)&Bl[sm][sk + 8] = *(const bf16x8*)(bp + 8);
        __syncthreads();

        bf16x8 af[4], bfr[4];
        #pragma unroll
        for (int mb = 0; mb < 4; ++mb)
            af[mb] = *(const bf16x8*)&Al[wm*64 + mb*16 + l15][8*g];
        #pragma unroll
        for (int nb = 0; nb < 4; ++nb)
            bfr[nb] = *(const bf16x8*)&Bl[wn*64 + nb*16 + l15][8*g];
        #pragma unroll
        for (int mb = 0; mb < 4; ++mb)
            #pragma unroll
            for (int nb = 0; nb < 4; ++nb)
                acc[mb][nb] = __builtin_amdgcn_mfma_f32_16x16x32_bf16(
                    af[mb], bfr[nb], acc[mb][nb], 0, 0, 0);
    }

    if (mode < 2) {
        #pragma unroll
        for (int mb = 0; mb < 4; ++mb)
            #pragma unroll
            for (int nb = 0; nb < 4; ++nb) {
                const int nh = col0 + wn*64 + nb*16 + l15;
                const float bv = bias[nh];
                #pragma unroll
                for (int r = 0; r < 4; ++r) {
                    const int row = row0 + wm*64 + mb*16 + 4*g + r;
                    const int b = row >> 11, s = row & 2047;
                    out[(((size_t)(b * N_HEADS + (nh >> 6)) * S_DIM + s) * H_DIM)
                        + (nh & 63)] = f2bf(acc[mb][nb][r] + bv);
                }
            }
    } else {
        // V: write transposed [B][N][H][S] via per-wave LDS bounce
        for (int mb = 0; mb < 4; ++mb)
            for (int nb = 0; nb < 4; ++nb) {
                const int nh = col0 + wn*64 + nb*16 + l15;
                const float bv = bias[nh];
                __syncthreads();
                #pragma unroll
                for (int r = 0; r < 4; ++r)
                    Tb[w][l15][4*g + r] = f2bf(acc[mb][nb][r] + bv);
                __syncthreads();
                const int nr = lane >> 2, mc = (lane & 3) * 4;
                const int nh2 = col0 + wn*64 + nb*16 + nr;
                const int row = row0 + wm*64 + mb*16 + mc;
                const int b = row >> 11, s = row & 2047;
                *(bf16x4*)&out[((size_t)(b * NH + nh2)) * S_DIM + s] =
                    *(bf16x4*)&Tb[w][nr][mc];
            }
    }
}

// ---------------------------------------------------------------------------
// Flash attention, bf16 MFMA. Block = 4 waves x 32 f-rows = 128 f for one (b,n).
// K/V tiles of 64 t staged in LDS; softmax in registers (16-lane shfl);
// P transposed through LDS into PV A-fragments.
// ---------------------------------------------------------------------------
__global__ __launch_bounds__(256)
void attn_mfma(const short* __restrict__ Qb, const short* __restrict__ Kb,
               const short* __restrict__ Vt,
               const unsigned long long* __restrict__ mp,
               float* __restrict__ out)
{
    __shared__ short Kl[64][72];
    __shared__ short Vl[64][72];
    __shared__ short Pl[128][72];

    const int tid  = threadIdx.x;
    const int lane = tid & 63, w = tid >> 6;
    const int g = lane >> 4, l15 = lane & 15;
    const int f0 = blockIdx.x * 128;
    const int n = blockIdx.y, b = blockIdx.z;

    const short* Qbase = Qb + (size_t)(b * N_HEADS + n) * S_DIM * H_DIM;
    const short* Kbase = Kb + (size_t)(b * N_HEADS + n) * S_DIM * H_DIM;
    const short* Vbase = Vt + (size_t)(b * NH + n * H_DIM) * S_DIM;

    bf16x8 qf[2][2];
    #pragma unroll
    for (int fs = 0; fs < 2; ++fs)
        #pragma unroll
        for (int hc = 0; hc < 2; ++hc)
            qf[fs][hc] = *(const bf16x8*)
                &Qbase[(size_t)(f0 + w*32 + fs*16 + l15) * H_DIM + hc*32 + 8*g];

    f32x4 o[2][4];
    float mrow[2][4], lrow[2][4];
    #pragma unroll
    for (int fs = 0; fs < 2; ++fs) {
        #pragma unroll
        for (int hb = 0; hb < 4; ++hb) o[fs][hb] = (f32x4){0.f, 0.f, 0.f, 0.f};
        #pragma unroll
        for (int r = 0; r < 4; ++r) { mrow[fs][r] = -1e30f; lrow[fs][r] = 0.f; }
    }

    const int sr = tid >> 2;           // staging row (t for K, h for V)
    const int sc = (tid & 3) * 16;     // staging col chunk

    for (int t0 = 0; t0 < S_DIM; t0 += 64) {
        __syncthreads();
        const short* kp = &Kbase[(size_t)(t0 + sr) * H_DIM + sc];
        *(bf16x8*)&Kl[sr][sc]     = *(const bf16x8*)kp;
        *(bf16x8*)&Kl[sr][sc + 8] = *(const bf16x8*)(kp + 8);
        const short* vp = &Vbase[(size_t)sr * S_DIM + t0 + sc];
        *(bf16x8*)&Vl[sr][sc]     = *(const bf16x8*)vp;
        *(bf16x8*)&Vl[sr][sc + 8] = *(const bf16x8*)(vp + 8);
        __syncthreads();

        #pragma unroll
        for (int fs = 0; fs < 2; ++fs) {
            f32x4 s[4];
            #pragma unroll
            for (int tb = 0; tb < 4; ++tb) {
                s[tb] = (f32x4){0.f, 0.f, 0.f, 0.f};
                #pragma unroll
                for (int hc = 0; hc < 2; ++hc) {
                    bf16x8 kf = *(const bf16x8*)&Kl[tb*16 + l15][hc*32 + 8*g];
                    s[tb] = __builtin_amdgcn_mfma_f32_16x16x32_bf16(
                        qf[fs][hc], kf, s[tb], 0, 0, 0);
                }
            }
            unsigned long long mk[4];
            #pragma unroll
            for (int r = 0; r < 4; ++r) {
                const int f = f0 + w*32 + fs*16 + 4*g + r;
                mk[r] = mp[((size_t)(b * S_DIM + f) << 5) + (t0 >> 6)];
            }
            #pragma unroll
            for (int r = 0; r < 4; ++r) {
                float sv[4];
                float mx = -INFINITY;
                #pragma unroll
                for (int tb = 0; tb < 4; ++tb) {
                    float x = s[tb][r] * 0.125f;
                    const int bit = (int)((mk[r] >> (tb*16 + l15)) & 1ULL);
                    x = bit ? x : -INFINITY;
                    sv[tb] = x;
                    mx = fmaxf(mx, x);
                }
                #pragma unroll
                for (int off = 1; off < 16; off <<= 1)
                    mx = fmaxf(mx, __shfl_xor(mx, off, 64));
                const float mnew = fmaxf(mrow[fs][r], mx);
                const float c = __expf(mrow[fs][r] - mnew);
                mrow[fs][r] = mnew;
                float ps = 0.f;
                #pragma unroll
                for (int tb = 0; tb < 4; ++tb) {
                    const float p = __expf(sv[tb] - mnew);
                    ps += p;
                    s[tb][r] = p;
                }
                #pragma unroll
                for (int off = 1; off < 16; off <<= 1)
                    ps += __shfl_xor(ps, off, 64);
                lrow[fs][r] = lrow[fs][r] * c + ps;
                #pragma unroll
                for (int hb = 0; hb < 4; ++hb) o[fs][hb][r] *= c;
            }
            #pragma unroll
            for (int tb = 0; tb < 4; ++tb)
                #pragma unroll
                for (int r = 0; r < 4; ++r)
                    Pl[w*32 + fs*16 + 4*g + r][tb*16 + l15] = f2bf(s[tb][r]);
        }
        __syncthreads();

        #pragma unroll
        for (int tc = 0; tc < 2; ++tc) {
            bf16x8 pa0 = *(const bf16x8*)&Pl[w*32 + l15][tc*32 + 8*g];
            bf16x8 pa1 = *(const bf16x8*)&Pl[w*32 + 16 + l15][tc*32 + 8*g];
            #pragma unroll
            for (int hb = 0; hb < 4; ++hb) {
                bf16x8 vf = *(const bf16x8*)&Vl[hb*16 + l15][tc*32 + 8*g];
                o[0][hb] = __builtin_amdgcn_mfma_f32_16x16x32_bf16(pa0, vf, o[0][hb], 0, 0, 0);
                o[1][hb] = __builtin_amdgcn_mfma_f32_16x16x32_bf16(pa1, vf, o[1][hb], 0, 0, 0);
            }
        }
    }

    #pragma unroll
    for (int fs = 0; fs < 2; ++fs)
        #pragma unroll
        for (int r = 0; r < 4; ++r) {
            const float inv = 1.0f / lrow[fs][r];
            const int f = f0 + w*32 + fs*16 + 4*g + r;
            #pragma unroll
            for (int hb = 0; hb < 4; ++hb)
                out[(((size_t)(b * S_DIM + f) * N_HEADS + n) * H_DIM) + hb*16 + l15]
                    = o[fs][hb][r] * inv;
        }
}

extern "C" void kernel_launch(void* const* d_in, const int* in_sizes, int n_in,
                              void* d_out, int out_size, void* d_ws, size_t ws_size,
                              hipStream_t stream)
{
    const float* from = (const float*)d_in[0];
    const float* to   = (const float*)d_in[1];
    const int*   mask = (const int*)d_in[2];
    const float* wq   = (const float*)d_in[3];
    const float* bq   = (const float*)d_in[4];
    const float* wk   = (const float*)d_in[5];
    const float* bk   = (const float*)d_in[6];
    const float* wv   = (const float*)d_in[7];
    const float* bv   = (const float*)d_in[8];
    float* out = (float*)d_out;

    // workspace carve (bytes): 5*8.39M + 3*2.10M + 1.05M = 49.28 MB
    char* p = (char*)d_ws;
    const size_t sz_x   = (size_t)M_DIM * D_DIM * 2;        // 8,388,608
    const size_t sz_w   = (size_t)NH * D_DIM * 2;           // 2,097,152
    const size_t sz_qkv = (size_t)B_DIM * N_HEADS * S_DIM * H_DIM * 2;
    short* Fb  = (short*)p;            p += sz_x;
    short* Tbf = (short*)p;            p += sz_x;
    short* Wtq = (short*)p;            p += sz_w;
    short* Wtk = (short*)p;            p += sz_w;
    short* Wtv = (short*)p;            p += sz_w;
    short* Qw  = (short*)p;            p += sz_qkv;
    short* Kw  = (short*)p;            p += sz_qkv;
    short* Vw  = (short*)p;            p += sz_qkv;
    unsigned long long* mpk = (unsigned long long*)p;       // 1,048,576

    const int n4 = (M_DIM * D_DIM) / 4;                     // 1,048,576
    cvt_bf16<<<n4 / 256, 256, 0, stream>>>(from, Fb, n4);
    cvt_bf16<<<n4 / 256, 256, 0, stream>>>(to, Tbf, n4);

    dim3 wg(16, 16);
    wtrans<<<wg, 256, 0, stream>>>(wq, Wtq);
    wtrans<<<wg, 256, 0, stream>>>(wk, Wtk);
    wtrans<<<wg, 256, 0, stream>>>(wv, Wtv);

    maskpack<<<256, 256, 0, stream>>>(mask, mpk, B_DIM * S_DIM * (S_DIM / 64));

    dim3 pg(M_DIM / 128, NH / 128);    // (32, 8)
    proj_mfma<<<pg, 256, 0, stream>>>(Fb,  Wtq, bq, Qw, 0);
    proj_mfma<<<pg, 256, 0, stream>>>(Tbf, Wtk, bk, Kw, 1);
    proj_mfma<<<pg, 256, 0, stream>>>(Tbf, Wtv, bv, Vw, 2);

    dim3 ag(S_DIM / 128, N_HEADS, B_DIM);  // (16, 16, 2)
    attn_mfma<<<ag, 256, 0, stream>>>(Qw, Kw, Vw, mpk, out);
}

// Round 3
// 183.630 us; speedup vs baseline: 6.2133x; 1.4567x over previous
//
#include <hip/hip_runtime.h>

#define B_DIM   2
#define S_DIM   2048
#define D_DIM   1024
#define N_HEADS 16
#define H_DIM   64
#define NH      1024
#define M_DIM   4096   // B * S

typedef short bf16x8 __attribute__((ext_vector_type(8)));
typedef short bf16x4 __attribute__((ext_vector_type(4)));
typedef float f32x4  __attribute__((ext_vector_type(4)));

__device__ __forceinline__ short f2bf(float x) {
    unsigned u = __float_as_uint(x);
    u = (u + 0x7fffu + ((u >> 16) & 1u)) >> 16;   // RNE
    return (short)u;
}

__device__ __forceinline__ void glds16(const void* g, void* l) {
    __builtin_amdgcn_global_load_lds(
        (const __attribute__((address_space(1))) unsigned int*)g,
        (__attribute__((address_space(3))) unsigned int*)l, 16, 0, 0);
}

#define VMCNT(n) asm volatile("s_waitcnt vmcnt(" #n ")" ::: "memory")

// ---------------------------------------------------------------------------
// f32 -> bf16 flat convert
// ---------------------------------------------------------------------------
__global__ __launch_bounds__(256)
void cvt_bf16(const float* __restrict__ src, short* __restrict__ dst, int n4) {
    int i = blockIdx.x * blockDim.x + threadIdx.x;
    if (i >= n4) return;
    float4 v = ((const float4*)src)[i];
    bf16x4 o;
    o[0] = f2bf(v.x); o[1] = f2bf(v.y); o[2] = f2bf(v.z); o[3] = f2bf(v.w);
    ((bf16x4*)dst)[i] = o;
}

// ---------------------------------------------------------------------------
// W [1024 d][1024 nh] f32 -> Wt [1024 nh][1024 d] bf16
// ---------------------------------------------------------------------------
__global__ __launch_bounds__(256)
void wtrans(const float* __restrict__ W, short* __restrict__ Wt) {
    __shared__ short T[64][66];
    const int d0 = blockIdx.x * 64, n0 = blockIdx.y * 64;
    const int tid = threadIdx.x;
    {
        const int dr = tid >> 2, nc = (tid & 3) * 16;
        const float* src = &W[(size_t)(d0 + dr) * NH + n0 + nc];
        float vv[16];
        #pragma unroll
        for (int q = 0; q < 4; ++q) {
            float4 v = ((const float4*)src)[q];
            vv[q*4+0] = v.x; vv[q*4+1] = v.y; vv[q*4+2] = v.z; vv[q*4+3] = v.w;
        }
        #pragma unroll
        for (int j = 0; j < 16; ++j) T[nc + j][dr] = f2bf(vv[j]);
    }
    __syncthreads();
    {
        const int nr = tid >> 2, dc = (tid & 3) * 16;
        short o[16];
        #pragma unroll
        for (int j = 0; j < 16; ++j) o[j] = T[nr][dc + j];
        short* dstp = &Wt[(size_t)(n0 + nr) * D_DIM + d0 + dc];
        *(bf16x8*)(dstp)     = *(bf16x8*)&o[0];
        *(bf16x8*)(dstp + 8) = *(bf16x8*)&o[8];
    }
}

// ---------------------------------------------------------------------------
// mask int32 [B][F][T] -> packed bits u64 [B][F][T/64]
// ---------------------------------------------------------------------------
__global__ __launch_bounds__(256)
void maskpack(const int* __restrict__ mask, unsigned long long* __restrict__ mp,
              int total) {
    const int lane = threadIdx.x & 63;
    const int wid  = (blockIdx.x * blockDim.x + threadIdx.x) >> 6;
    const int nw   = (gridDim.x * blockDim.x) >> 6;
    for (int idx = wid; idx < total; idx += nw) {
        int m = mask[(size_t)idx * 64 + lane];
        unsigned long long bits = __ballot(m != 0);
        if (lane == 0) mp[idx] = bits;
    }
}

// ---------------------------------------------------------------------------
// Fused QKV projection. Grid (32, 24): blockIdx.y 0-7 = Q (from_tensor),
// 8-15 = K, 16-23 = V (to_tensor). Wt = [3072][1024] bf16 (Q,K,V stacked).
// 128x128 tile, BK=32, glds dbuf staging, chunk-swizzle c^((r>>1)&3).
// Q scaled by 0.125 (folds 1/sqrt(H) into attention's QK^T).
// Q/K out: [B][N][S][H] bf16; V out: [B][N][H][S] bf16.
// ---------------------------------------------------------------------------
__global__ __launch_bounds__(256)
void proj_mfma(const short* __restrict__ Fb, const short* __restrict__ Tb_,
               const short* __restrict__ Wt,
               const float* __restrict__ bq, const float* __restrict__ bk,
               const float* __restrict__ bv,
               short* __restrict__ Qo, short* __restrict__ Ko,
               short* __restrict__ Vo)
{
    __shared__ short Al[2][4096];   // [buf][row*32 + chunk-swizzled]
    __shared__ short Bl[2][4096];
    __shared__ short Tt[4][16][20]; // per-wave transpose bounce

    const int tid  = threadIdx.x;
    const int lane = tid & 63, w = tid >> 6;
    const int g = lane >> 4, l15 = lane & 15;
    const int wm = w >> 1, wn = w & 1;
    const int row0 = blockIdx.x * 128;
    const int region = blockIdx.y >> 3;            // 0=Q 1=K 2=V
    const short* X = (region == 0) ? Fb : Tb_;

    // glds source mapping (per lane): physical chunk = lane-linear,
    // logical chunk = (lane&3) ^ ((lane>>3)&3)
    const int rA0   = w * 32 + (lane >> 2);
    const int cl8   = ((lane & 3) ^ ((lane >> 3) & 3)) * 8;
    const size_t aOff0 = (size_t)rA0 * D_DIM + cl8;
    const size_t aOff1 = aOff0 + 16 * D_DIM;
    const short* Abase = X + (size_t)row0 * D_DIM;
    const short* Bbase = Wt + (size_t)blockIdx.y * 128 * D_DIM;

    const int swz3 = (l15 >> 1) & 3;               // fragment-read swizzle

    f32x4 acc[4][4];
    #pragma unroll
    for (int i = 0; i < 4; ++i)
        #pragma unroll
        for (int j = 0; j < 4; ++j)
            acc[i][j] = (f32x4){0.f, 0.f, 0.f, 0.f};

    // prologue: stage k-tile 0 into buf 0
    glds16(Abase + aOff0, &Al[0][w * 1024]);
    glds16(Abase + aOff1, &Al[0][w * 1024 + 512]);
    glds16(Bbase + aOff0, &Bl[0][w * 1024]);
    glds16(Bbase + aOff1, &Bl[0][w * 1024 + 512]);

    for (int kt = 0; kt < 32; ++kt) {
        const int cur = kt & 1;
        if (kt < 31) {
            const int k1 = (kt + 1) * 32;
            glds16(Abase + k1 + aOff0, &Al[cur ^ 1][w * 1024]);
            glds16(Abase + k1 + aOff1, &Al[cur ^ 1][w * 1024 + 512]);
            glds16(Bbase + k1 + aOff0, &Bl[cur ^ 1][w * 1024]);
            glds16(Bbase + k1 + aOff1, &Bl[cur ^ 1][w * 1024 + 512]);
            VMCNT(4);
        } else {
            VMCNT(0);
        }
        __builtin_amdgcn_s_barrier();

        bf16x8 af[4], bfr[4];
        #pragma unroll
        for (int mb = 0; mb < 4; ++mb)
            af[mb] = *(const bf16x8*)&Al[cur][(wm*64 + mb*16 + l15)*32 + (g ^ swz3)*8];
        #pragma unroll
        for (int nb = 0; nb < 4; ++nb)
            bfr[nb] = *(const bf16x8*)&Bl[cur][(wn*64 + nb*16 + l15)*32 + (g ^ swz3)*8];
        #pragma unroll
        for (int mb = 0; mb < 4; ++mb)
            #pragma unroll
            for (int nb = 0; nb < 4; ++nb)
                acc[mb][nb] = __builtin_amdgcn_mfma_f32_16x16x32_bf16(
                    af[mb], bfr[nb], acc[mb][nb], 0, 0, 0);
        __builtin_amdgcn_s_barrier();
    }

    const float* bias = (region == 0) ? bq : (region == 1) ? bk : bv;
    const float scale = (region == 0) ? 0.125f : 1.0f;
    const int colL0 = (blockIdx.y & 7) * 128 + wn * 64;

    if (region < 2) {
        short* Out = (region == 0) ? Qo : Ko;
        #pragma unroll
        for (int mb = 0; mb < 4; ++mb)
            #pragma unroll
            for (int nb = 0; nb < 4; ++nb) {
                const float bvv = bias[colL0 + nb*16 + l15];
                // bounce: Tt[w][s_local 4g+r][h_local l15]
                #pragma unroll
                for (int r = 0; r < 4; ++r)
                    Tt[w][4*g + r][l15] =
                        f2bf((acc[mb][nb][r] + bvv) * scale);
                // read back: s_local = l15, h quad = g
                bf16x4 t4 = *(const bf16x4*)&Tt[w][l15][4*g];
                const int sg  = row0 + wm*64 + mb*16 + l15;
                const int bb  = sg >> 11, s = sg & 2047;
                const int cg  = colL0 + nb*16 + 4*g;
                const int n   = cg >> 6, hh = cg & 63;
                *(bf16x4*)&Out[(((size_t)(bb*N_HEADS + n)*S_DIM + s) << 6) + hh] = t4;
            }
    } else {
        // V transposed [B][NH][S]: thread holds 4 consecutive s for fixed nh
        #pragma unroll
        for (int mb = 0; mb < 4; ++mb)
            #pragma unroll
            for (int nb = 0; nb < 4; ++nb) {
                const int nhv = colL0 + nb*16 + l15;
                const float bvv = bias[nhv];
                bf16x4 t4;
                #pragma unroll
                for (int r = 0; r < 4; ++r)
                    t4[r] = f2bf(acc[mb][nb][r] + bvv);
                const int s4 = row0 + wm*64 + mb*16 + 4*g;
                const int bb = s4 >> 11, s = s4 & 2047;
                *(bf16x4*)&Vo[((size_t)(bb*NH + nhv) << 11) + s] = t4;
            }
    }
}

// ---------------------------------------------------------------------------
// Flash attention: no-max online softmax (scores bounded), swapped QK^T,
// cvt_pk P-pack, glds dbuf K/V staging with chunk^(r&7) swizzle.
// Grid (16, 16, 2); 4 waves x 32 f-rows.
// ---------------------------------------------------------------------------
__global__ __launch_bounds__(256)
void attn_mfma(const short* __restrict__ Qb, const short* __restrict__ Kb,
               const short* __restrict__ Vt,
               const unsigned long long* __restrict__ mp,
               float* __restrict__ out)
{
    __shared__ short Kl[2][4096];   // [buf][row*64 + swizzled chunk]
    __shared__ short Vl[2][4096];
    __shared__ short Pl[128 * 72];

    const int tid  = threadIdx.x;
    const int lane = tid & 63, w = tid >> 6;
    const int g = lane >> 4, l15 = lane & 15;
    const int f0 = blockIdx.x * 128;
    const int n  = blockIdx.y, b = blockIdx.z;

    const short* Qbase = Qb + (size_t)(b*N_HEADS + n) * S_DIM * H_DIM;
    const short* Kbase = Kb + (size_t)(b*N_HEADS + n) * S_DIM * H_DIM;
    const short* Vbase = Vt + (size_t)(b*NH + n*H_DIM) * S_DIM;

    // Q fragments (B-operand: col = f = l15, k = hc*32 + 8g + j)
    bf16x8 qf[2][2];
    #pragma unroll
    for (int fs = 0; fs < 2; ++fs)
        #pragma unroll
        for (int hc = 0; hc < 2; ++hc)
            qf[fs][hc] = *(const bf16x8*)
                &Qbase[(size_t)(f0 + w*32 + fs*16 + l15) * H_DIM + hc*32 + 8*g];

    // glds mapping: row = w*16 + q*8 + (lane>>3); logical chunk = (lane&7)^(lane>>3)
    const int rk  = w * 16 + (lane >> 3);
    const int cl8 = ((lane & 7) ^ (lane >> 3)) * 8;
    const size_t kOff0 = (size_t)rk * H_DIM + cl8;
    const size_t kOff1 = kOff0 + 8 * H_DIM;
    const size_t vOff0 = (size_t)rk * S_DIM + cl8;
    const size_t vOff1 = vOff0 + 8 * S_DIM;

    const unsigned long long* mr0 =
        mp + ((size_t)(b*S_DIM + f0 + w*32 + l15) << 5);
    const unsigned long long* mr1 = mr0 + (16 << 5);

    const int swz7 = l15 & 7;

    f32x4 o[2][4];
    #pragma unroll
    for (int fs = 0; fs < 2; ++fs)
        #pragma unroll
        for (int hb = 0; hb < 4; ++hb)
            o[fs][hb] = (f32x4){0.f, 0.f, 0.f, 0.f};
    float lsum[2] = {0.f, 0.f};

    // prologue: stage tile 0
    glds16(Kbase + kOff0, &Kl[0][w * 1024]);
    glds16(Kbase + kOff1, &Kl[0][w * 1024 + 512]);
    glds16(Vbase + vOff0, &Vl[0][w * 1024]);
    glds16(Vbase + vOff1, &Vl[0][w * 1024 + 512]);

    for (int tt = 0; tt < 32; ++tt) {
        const int cur = tt & 1;
        const int t0  = tt * 64;

        // mask prefetch FIRST (retires before glds in the FIFO)
        const unsigned long long mk0 = mr0[tt];
        const unsigned long long mk1 = mr1[tt];
        __builtin_amdgcn_sched_barrier(0);

        if (tt < 31) {
            const int t1 = t0 + 64;
            glds16(Kbase + (size_t)t1*H_DIM + kOff0, &Kl[cur^1][w*1024]);
            glds16(Kbase + (size_t)t1*H_DIM + kOff1, &Kl[cur^1][w*1024 + 512]);
            glds16(Vbase + t1 + vOff0, &Vl[cur^1][w*1024]);
            glds16(Vbase + t1 + vOff1, &Vl[cur^1][w*1024 + 512]);
            VMCNT(4);
        } else {
            VMCNT(0);
        }
        __builtin_amdgcn_s_barrier();

        // K fragments (A-operand: row = t = l15, k = hc*32 + 8g + j)
        bf16x8 kf[4][2];
        #pragma unroll
        for (int tb = 0; tb < 4; ++tb)
            #pragma unroll
            for (int hc = 0; hc < 2; ++hc)
                kf[tb][hc] = *(const bf16x8*)
                    &Kl[cur][(tb*16 + l15)*64 + ((4*hc + g) ^ swz7)*8];

        // QK^T (swapped: D[t][f]) + no-max softmax + P pack
        #pragma unroll
        for (int fs = 0; fs < 2; ++fs) {
            f32x4 sv[4];
            #pragma unroll
            for (int tb = 0; tb < 4; ++tb) {
                sv[tb] = (f32x4){0.f, 0.f, 0.f, 0.f};
                sv[tb] = __builtin_amdgcn_mfma_f32_16x16x32_bf16(
                    kf[tb][0], qf[fs][0], sv[tb], 0, 0, 0);
                sv[tb] = __builtin_amdgcn_mfma_f32_16x16x32_bf16(
                    kf[tb][1], qf[fs][1], sv[tb], 0, 0, 0);
            }
            const unsigned long long mk = fs ? mk1 : mk0;
            float lp = 0.f;
            short* prow = &Pl[(w*32 + fs*16 + l15) * 72];
            #pragma unroll
            for (int tb = 0; tb < 4; ++tb) {
                const unsigned mb_ = (unsigned)(mk >> (tb*16 + 4*g));
                float p0 = (mb_ & 1u) ? __expf(sv[tb][0]) : 0.f;
                float p1 = (mb_ & 2u) ? __expf(sv[tb][1]) : 0.f;
                float p2 = (mb_ & 4u) ? __expf(sv[tb][2]) : 0.f;
                float p3 = (mb_ & 8u) ? __expf(sv[tb][3]) : 0.f;
                lp += (p0 + p1) + (p2 + p3);
                unsigned u0, u1;
                asm("v_cvt_pk_bf16_f32 %0, %1, %2" : "=v"(u0) : "v"(p0), "v"(p1));
                asm("v_cvt_pk_bf16_f32 %0, %1, %2" : "=v"(u1) : "v"(p2), "v"(p3));
                *(unsigned*)&prow[tb*16 + 4*g]     = u0;
                *(unsigned*)&prow[tb*16 + 4*g + 2] = u1;
            }
            lsum[fs] += lp;
        }

        // PV: A = P (row=f=l15, k=t), B = V^T (col=h=l15, k=t)
        #pragma unroll
        for (int tc = 0; tc < 2; ++tc) {
            bf16x8 pa0 = *(const bf16x8*)&Pl[(w*32 + l15)*72      + tc*32 + 8*g];
            bf16x8 pa1 = *(const bf16x8*)&Pl[(w*32 + 16 + l15)*72 + tc*32 + 8*g];
            #pragma unroll
            for (int hb = 0; hb < 4; ++hb) {
                bf16x8 vf = *(const bf16x8*)
                    &Vl[cur][(hb*16 + l15)*64 + ((4*tc + g) ^ swz7)*8];
                o[0][hb] = __builtin_amdgcn_mfma_f32_16x16x32_bf16(pa0, vf, o[0][hb], 0, 0, 0);
                o[1][hb] = __builtin_amdgcn_mfma_f32_16x16x32_bf16(pa1, vf, o[1][hb], 0, 0, 0);
            }
        }
        __builtin_amdgcn_s_barrier();
    }

    // deferred row-sum: reduce partials across the 4 g-groups
    #pragma unroll
    for (int fs = 0; fs < 2; ++fs) {
        float v = lsum[fs];
        v += __shfl_xor(v, 16, 64);
        v += __shfl_xor(v, 32, 64);
        lsum[fs] = v;
    }
    #pragma unroll
    for (int fs = 0; fs < 2; ++fs)
        #pragma unroll
        for (int r = 0; r < 4; ++r) {
            const float inv = 1.0f / __shfl(lsum[fs], 4*g + r, 64);
            const int f = f0 + w*32 + fs*16 + 4*g + r;
            #pragma unroll
            for (int hb = 0; hb < 4; ++hb)
                out[(((size_t)(b*S_DIM + f)*N_HEADS + n) << 6) + hb*16 + l15]
                    = o[fs][hb][r] * inv;
        }
}

extern "C" void kernel_launch(void* const* d_in, const int* in_sizes, int n_in,
                              void* d_out, int out_size, void* d_ws, size_t ws_size,
                              hipStream_t stream)
{
    const float* from = (const float*)d_in[0];
    const float* to   = (const float*)d_in[1];
    const int*   mask = (const int*)d_in[2];
    const float* wq   = (const float*)d_in[3];
    const float* bq   = (const float*)d_in[4];
    const float* wk   = (const float*)d_in[5];
    const float* bk   = (const float*)d_in[6];
    const float* wv   = (const float*)d_in[7];
    const float* bv   = (const float*)d_in[8];
    float* out = (float*)d_out;

    char* p = (char*)d_ws;
    const size_t sz_x   = (size_t)M_DIM * D_DIM * 2;
    const size_t sz_w   = (size_t)NH * D_DIM * 2;
    const size_t sz_qkv = (size_t)B_DIM * N_HEADS * S_DIM * H_DIM * 2;
    short* Fb  = (short*)p;            p += sz_x;
    short* Tbf = (short*)p;            p += sz_x;
    short* Wtq = (short*)p;            p += sz_w;   // Wtq,Wtk,Wtv adjacent
    short* Wtk = (short*)p;            p += sz_w;
    short* Wtv = (short*)p;            p += sz_w;
    short* Qw  = (short*)p;            p += sz_qkv;
    short* Kw  = (short*)p;            p += sz_qkv;
    short* Vw  = (short*)p;            p += sz_qkv;
    unsigned long long* mpk = (unsigned long long*)p;

    const int n4 = (M_DIM * D_DIM) / 4;
    cvt_bf16<<<n4 / 256, 256, 0, stream>>>(from, Fb, n4);
    cvt_bf16<<<n4 / 256, 256, 0, stream>>>(to, Tbf, n4);

    dim3 wg(16, 16);
    wtrans<<<wg, 256, 0, stream>>>(wq, Wtq);
    wtrans<<<wg, 256, 0, stream>>>(wk, Wtk);
    wtrans<<<wg, 256, 0, stream>>>(wv, Wtv);

    maskpack<<<256, 256, 0, stream>>>(mask, mpk, B_DIM * S_DIM * (S_DIM / 64));

    dim3 pg(M_DIM / 128, 24);
    proj_mfma<<<pg, 256, 0, stream>>>(Fb, Tbf, Wtq, bq, bk, bv, Qw, Kw, Vw);

    dim3 ag(S_DIM / 128, N_HEADS, B_DIM);
    attn_mfma<<<ag, 256, 0, stream>>>(Qw, Kw, Vw, mpk, out);
}

// Round 5
// 155.936 us; speedup vs baseline: 7.3168x; 1.1776x over previous
//
#include <hip/hip_runtime.h>

#define B_DIM   2
#define S_DIM   2048
#define D_DIM   1024
#define N_HEADS 16
#define H_DIM   64
#define NH      1024
#define M_DIM   4096   // B * S

typedef short bf16x8 __attribute__((ext_vector_type(8)));
typedef short bf16x4 __attribute__((ext_vector_type(4)));
typedef float f32x4  __attribute__((ext_vector_type(4)));

// exact power-of-two scale folded into Q (1/sqrt(64)); exp stays natural
#define QSCALE 0.125f

__device__ __forceinline__ short f2bf(float x) {
    unsigned u = __float_as_uint(x);
    u = (u + 0x7fffu + ((u >> 16) & 1u)) >> 16;   // RNE
    return (short)u;
}

__device__ __forceinline__ void glds16(const void* g, void* l) {
    __builtin_amdgcn_global_load_lds(
        (const __attribute__((address_space(1))) unsigned int*)g,
        (__attribute__((address_space(3))) unsigned int*)l, 16, 0, 0);
}

#define VMCNT(n) asm volatile("s_waitcnt vmcnt(" #n ")" ::: "memory")

#if __has_builtin(__builtin_amdgcn_mfma_f32_16x16x16bf16_1k)
#define MFMA16(a, b, c) __builtin_amdgcn_mfma_f32_16x16x16bf16_1k(a, b, c, 0, 0, 0)
#else
// Fallback: tie D==C ("0"), so output can't silently alias A/B; generous nops.
__device__ __forceinline__ f32x4 mfma16_fb(bf16x4 a, bf16x4 b, f32x4 c) {
    f32x4 d;
    asm volatile("v_mfma_f32_16x16x16_bf16 %0, %2, %3, %1\n\t"
                 "s_nop 7\n\ts_nop 3"
                 : "=v"(d) : "0"(c), "v"(a), "v"(b));
    return d;
}
#define MFMA16(a, b, c) mfma16_fb(a, b, c)
#endif

// ---------------------------------------------------------------------------
// f32 -> bf16 convert, both input tensors in one launch
// ---------------------------------------------------------------------------
__global__ __launch_bounds__(256)
void cvt_bf16_2(const float* __restrict__ a, const float* __restrict__ b,
                short* __restrict__ da, short* __restrict__ db) {
    const int n4 = (M_DIM * D_DIM) / 4;
    int i = blockIdx.x * blockDim.x + threadIdx.x;
    const float* s = (i < n4) ? a : b;
    short* d = (i < n4) ? da : db;
    int j = (i < n4) ? i : i - n4;
    float4 v = ((const float4*)s)[j];
    bf16x4 o;
    o[0] = f2bf(v.x); o[1] = f2bf(v.y); o[2] = f2bf(v.z); o[3] = f2bf(v.w);
    ((bf16x4*)d)[j] = o;
}

// ---------------------------------------------------------------------------
// W [1024 d][1024 nh] f32 -> Wt [1024 nh][1024 d] bf16; z selects wq/wk/wv
// ---------------------------------------------------------------------------
__global__ __launch_bounds__(256)
void wtrans3(const float* __restrict__ wq, const float* __restrict__ wk,
             const float* __restrict__ wv, short* __restrict__ Wt) {
    __shared__ short T[64][66];
    const int z = blockIdx.z;
    const float* W = (z == 0) ? wq : (z == 1) ? wk : wv;
    short* dst = Wt + (size_t)z * NH * D_DIM;
    const int d0 = blockIdx.x * 64, n0 = blockIdx.y * 64;
    const int tid = threadIdx.x;
    {
        const int dr = tid >> 2, nc = (tid & 3) * 16;
        const float* src = &W[(size_t)(d0 + dr) * NH + n0 + nc];
        float vv[16];
        #pragma unroll
        for (int q = 0; q < 4; ++q) {
            float4 v = ((const float4*)src)[q];
            vv[q*4+0] = v.x; vv[q*4+1] = v.y; vv[q*4+2] = v.z; vv[q*4+3] = v.w;
        }
        #pragma unroll
        for (int j = 0; j < 16; ++j) T[nc + j][dr] = f2bf(vv[j]);
    }
    __syncthreads();
    {
        const int nr = tid >> 2, dc = (tid & 3) * 16;
        short o[16];
        #pragma unroll
        for (int j = 0; j < 16; ++j) o[j] = T[nr][dc + j];
        short* dstp = &dst[(size_t)(n0 + nr) * D_DIM + d0 + dc];
        *(bf16x8*)(dstp)     = *(bf16x8*)&o[0];
        *(bf16x8*)(dstp + 8) = *(bf16x8*)&o[8];
    }
}

// ---------------------------------------------------------------------------
// mask int32 [B][F][T] -> packed bits u64 [B][F][T/64]
// ---------------------------------------------------------------------------
__global__ __launch_bounds__(256)
void maskpack(const int* __restrict__ mask, unsigned long long* __restrict__ mp,
              int total) {
    const int lane = threadIdx.x & 63;
    const int wid  = (blockIdx.x * blockDim.x + threadIdx.x) >> 6;
    const int nw   = (gridDim.x * blockDim.x) >> 6;
    for (int idx = wid; idx < total; idx += nw) {
        int m = mask[(size_t)idx * 64 + lane];
        unsigned long long bits = __ballot(m != 0);
        if (lane == 0) mp[idx] = bits;
    }
}

// ---------------------------------------------------------------------------
// Fused QKV projection. Grid (32, 24): y 0-7 = Q, 8-15 = K, 16-23 = V.
// Wt = [3072][1024] bf16 stacked. Q scaled by 0.125 (exact).
// Q/K out: [B][N][S][H] bf16; V out: [B][N][H][S] bf16 (transposed).
// ---------------------------------------------------------------------------
__global__ __launch_bounds__(256)
void proj_mfma(const short* __restrict__ Fb, const short* __restrict__ Tb_,
               const short* __restrict__ Wt,
               const float* __restrict__ bq, const float* __restrict__ bk,
               const float* __restrict__ bv,
               short* __restrict__ Qo, short* __restrict__ Ko,
               short* __restrict__ Vo)
{
    __shared__ short Al[2][4096];
    __shared__ short Bl[2][4096];
    __shared__ short Tt[4][16][20];

    const int tid  = threadIdx.x;
    const int lane = tid & 63, w = tid >> 6;
    const int g = lane >> 4, l15 = lane & 15;
    const int wm = w >> 1, wn = w & 1;
    const int row0 = blockIdx.x * 128;
    const int region = blockIdx.y >> 3;            // 0=Q 1=K 2=V
    const short* X = (region == 0) ? Fb : Tb_;

    const int cl8   = ((lane & 3) ^ ((lane >> 3) & 3)) * 8;
    const size_t aOff0 = (size_t)(w * 32 + (lane >> 2)) * D_DIM + cl8;
    const size_t aOff1 = aOff0 + 16 * D_DIM;
    const short* Abase = X + (size_t)row0 * D_DIM;
    const short* Bbase = Wt + (size_t)blockIdx.y * 128 * D_DIM;

    const int swz3 = (l15 >> 1) & 3;

    f32x4 acc[4][4];
    #pragma unroll
    for (int i = 0; i < 4; ++i)
        #pragma unroll
        for (int j = 0; j < 4; ++j)
            acc[i][j] = (f32x4){0.f, 0.f, 0.f, 0.f};

    glds16(Abase + aOff0, &Al[0][w * 1024]);
    glds16(Abase + aOff1, &Al[0][w * 1024 + 512]);
    glds16(Bbase + aOff0, &Bl[0][w * 1024]);
    glds16(Bbase + aOff1, &Bl[0][w * 1024 + 512]);

    for (int kt = 0; kt < 32; ++kt) {
        const int cur = kt & 1;
        if (kt < 31) {
            const int k1 = (kt + 1) * 32;
            glds16(Abase + k1 + aOff0, &Al[cur ^ 1][w * 1024]);
            glds16(Abase + k1 + aOff1, &Al[cur ^ 1][w * 1024 + 512]);
            glds16(Bbase + k1 + aOff0, &Bl[cur ^ 1][w * 1024]);
            glds16(Bbase + k1 + aOff1, &Bl[cur ^ 1][w * 1024 + 512]);
            VMCNT(4);
        } else {
            VMCNT(0);
        }
        __builtin_amdgcn_s_barrier();

        bf16x8 af[4], bfr[4];
        #pragma unroll
        for (int mb = 0; mb < 4; ++mb)
            af[mb] = *(const bf16x8*)&Al[cur][(wm*64 + mb*16 + l15)*32 + (g ^ swz3)*8];
        #pragma unroll
        for (int nb = 0; nb < 4; ++nb)
            bfr[nb] = *(const bf16x8*)&Bl[cur][(wn*64 + nb*16 + l15)*32 + (g ^ swz3)*8];
        #pragma unroll
        for (int mb = 0; mb < 4; ++mb)
            #pragma unroll
            for (int nb = 0; nb < 4; ++nb)
                acc[mb][nb] = __builtin_amdgcn_mfma_f32_16x16x32_bf16(
                    af[mb], bfr[nb], acc[mb][nb], 0, 0, 0);
        __builtin_amdgcn_s_barrier();
    }

    const float* bias = (region == 0) ? bq : (region == 1) ? bk : bv;
    const float scale = (region == 0) ? QSCALE : 1.0f;
    const int colL0 = (blockIdx.y & 7) * 128 + wn * 64;

    if (region < 2) {
        short* Out = (region == 0) ? Qo : Ko;
        #pragma unroll
        for (int mb = 0; mb < 4; ++mb)
            #pragma unroll
            for (int nb = 0; nb < 4; ++nb) {
                const float bvv = bias[colL0 + nb*16 + l15];
                #pragma unroll
                for (int r = 0; r < 4; ++r)
                    Tt[w][4*g + r][l15] = f2bf((acc[mb][nb][r] + bvv) * scale);
                bf16x4 t4 = *(const bf16x4*)&Tt[w][l15][4*g];
                const int sg  = row0 + wm*64 + mb*16 + l15;
                const int bb  = sg >> 11, s = sg & 2047;
                const int cg  = colL0 + nb*16 + 4*g;
                const int n   = cg >> 6, hh = cg & 63;
                *(bf16x4*)&Out[(((size_t)(bb*N_HEADS + n)*S_DIM + s) << 6) + hh] = t4;
            }
    } else {
        #pragma unroll
        for (int mb = 0; mb < 4; ++mb)
            #pragma unroll
            for (int nb = 0; nb < 4; ++nb) {
                const int nhv = colL0 + nb*16 + l15;
                const float bvv = bias[nhv];
                bf16x4 t4;
                #pragma unroll
                for (int r = 0; r < 4; ++r)
                    t4[r] = f2bf(acc[mb][nb][r] + bvv);
                const int s4 = row0 + wm*64 + mb*16 + 4*g;
                const int bb = s4 >> 11, s = s4 & 2047;
                *(bf16x4*)&Vo[((size_t)(bb*NH + nhv) << 11) + s] = t4;
            }
    }
}

// ---------------------------------------------------------------------------
// Flash attention v5: swapped QK^T (16x16x32); P kept in registers as the
// B-fragment of 16x16x16 PV MFMAs (O^T[h][f]); __expf + ternary f32 mask
// zeroing (r3-proven); denominator via ones-MFMA (lane-local normalize).
// Grid (16, 16, 2); 4 waves x 32 f-rows; LDS = K/V dbuf only (~33KB).
// ---------------------------------------------------------------------------
__global__ __launch_bounds__(256)
void attn_mfma(const short* __restrict__ Qb, const short* __restrict__ Kb,
               const short* __restrict__ Vt,
               const unsigned long long* __restrict__ mp,
               float* __restrict__ out)
{
    __shared__ short Kl[2][4096];   // [buf][t-row * 64 + swizzled chunk]
    __shared__ short Vl[2][4096];   // [buf][h-row * 64 + swizzled chunk]

    const int tid  = threadIdx.x;
    const int lane = tid & 63, w = tid >> 6;
    const int g = lane >> 4, l15 = lane & 15;
    const int f0 = blockIdx.x * 128;
    const int n  = blockIdx.y, b = blockIdx.z;

    const short* Qbase = Qb + (size_t)(b*N_HEADS + n) * S_DIM * H_DIM;
    const short* Kbase = Kb + (size_t)(b*N_HEADS + n) * S_DIM * H_DIM;
    const short* Vbase = Vt + (size_t)(b*NH + n*H_DIM) * S_DIM;

    // Q B-fragments for swapped QK^T: col=f=l15, k = hc*32 + 8g + {0..7}
    bf16x8 qf[2][2];
    #pragma unroll
    for (int fs = 0; fs < 2; ++fs)
        #pragma unroll
        for (int hc = 0; hc < 2; ++hc)
            qf[fs][hc] = *(const bf16x8*)
                &Qbase[(size_t)(f0 + w*32 + fs*16 + l15) * H_DIM + hc*32 + 8*g];

    const int rk  = w * 16 + (lane >> 3);
    const int cl8 = ((lane & 7) ^ (lane >> 3)) * 8;
    const size_t kOff0 = (size_t)rk * H_DIM + cl8;
    const size_t kOff1 = kOff0 + 8 * H_DIM;
    const size_t vOff0 = (size_t)rk * S_DIM + cl8;
    const size_t vOff1 = vOff0 + 8 * S_DIM;

    const unsigned long long* mrp =
        mp + ((size_t)(b*S_DIM + f0 + w*32 + l15) << 5);

    const int swz7 = l15 & 7;
    const bf16x4 ones = {0x3F80, 0x3F80, 0x3F80, 0x3F80};   // bf16 1.0 x4

    f32x4 o2[2][4];     // O^T: row h = hb*16 + 4g + r, col f = l15
    f32x4 lacc[2];      // denominator (all 4 regs equal per lane)
    #pragma unroll
    for (int fs = 0; fs < 2; ++fs) {
        #pragma unroll
        for (int hb = 0; hb < 4; ++hb) o2[fs][hb] = (f32x4){0.f, 0.f, 0.f, 0.f};
        lacc[fs] = (f32x4){0.f, 0.f, 0.f, 0.f};
    }

    glds16(Kbase + kOff0, &Kl[0][w * 1024]);
    glds16(Kbase + kOff1, &Kl[0][w * 1024 + 512]);
    glds16(Vbase + vOff0, &Vl[0][w * 1024]);
    glds16(Vbase + vOff1, &Vl[0][w * 1024 + 512]);

    for (int tt = 0; tt < 32; ++tt) {
        const int cur = tt & 1;

        const unsigned long long mk0 = mrp[tt];
        const unsigned long long mk1 = mrp[tt + 512];
        __builtin_amdgcn_sched_barrier(0);

        if (tt < 31) {
            const int t1 = (tt + 1) * 64;
            glds16(Kbase + (size_t)t1*H_DIM + kOff0, &Kl[cur^1][w*1024]);
            glds16(Kbase + (size_t)t1*H_DIM + kOff1, &Kl[cur^1][w*1024 + 512]);
            glds16(Vbase + t1 + vOff0, &Vl[cur^1][w*1024]);
            glds16(Vbase + t1 + vOff1, &Vl[cur^1][w*1024 + 512]);
            VMCNT(4);
        } else {
            VMCNT(0);
        }
        __builtin_amdgcn_s_barrier();

        // ---- QK^T + mask-zero + exp -> P fragments (registers only) ----
        bf16x4 pfrag[2][4];   // [fs][tb]: P[t=16tb+4g+r][f=l15]
        #pragma unroll
        for (int tb = 0; tb < 4; ++tb) {
            bf16x8 kf0 = *(const bf16x8*)
                &Kl[cur][(tb*16 + l15)*64 + ((g    ) ^ swz7)*8];
            bf16x8 kf1 = *(const bf16x8*)
                &Kl[cur][(tb*16 + l15)*64 + ((4 + g) ^ swz7)*8];
            const f32x4 z = (f32x4){0.f, 0.f, 0.f, 0.f};
            f32x4 s0 = __builtin_amdgcn_mfma_f32_16x16x32_bf16(kf0, qf[0][0], z, 0, 0, 0);
            s0 = __builtin_amdgcn_mfma_f32_16x16x32_bf16(kf1, qf[0][1], s0, 0, 0, 0);
            f32x4 s1 = __builtin_amdgcn_mfma_f32_16x16x32_bf16(kf0, qf[1][0], z, 0, 0, 0);
            s1 = __builtin_amdgcn_mfma_f32_16x16x32_bf16(kf1, qf[1][1], s1, 0, 0, 0);
            #pragma unroll
            for (int fs = 0; fs < 2; ++fs) {
                const f32x4 sv = fs ? s1 : s0;
                const unsigned long long mk = fs ? mk1 : mk0;
                const unsigned mb_ = (unsigned)(mk >> (tb*16 + 4*g));
                float p0 = (mb_ & 1u) ? __expf(sv[0]) : 0.f;
                float p1 = (mb_ & 2u) ? __expf(sv[1]) : 0.f;
                float p2 = (mb_ & 4u) ? __expf(sv[2]) : 0.f;
                float p3 = (mb_ & 8u) ? __expf(sv[3]) : 0.f;
                unsigned u0, u1;
                asm("v_cvt_pk_bf16_f32 %0, %1, %2" : "=v"(u0) : "v"(p0), "v"(p1));
                asm("v_cvt_pk_bf16_f32 %0, %1, %2" : "=v"(u1) : "v"(p2), "v"(p3));
                union { unsigned u[2]; bf16x4 v; } pk;
                pk.u[0] = u0;
                pk.u[1] = u1;
                pfrag[fs][tb] = pk.v;
            }
        }

        // ---- PV: O^T[h][f] += V^T-frag x P-frag; denominator via ones ----
        #pragma unroll
        for (int tb = 0; tb < 4; ++tb) {
            #pragma unroll
            for (int hb = 0; hb < 4; ++hb) {
                bf16x4 va = *(const bf16x4*)
                    &Vl[cur][(hb*16 + l15)*64
                             + ((2*tb + (g>>1)) ^ swz7)*8 + (g & 1)*4];
                o2[0][hb] = MFMA16(va, pfrag[0][tb], o2[0][hb]);
                o2[1][hb] = MFMA16(va, pfrag[1][tb], o2[1][hb]);
            }
            lacc[0] = MFMA16(ones, pfrag[0][tb], lacc[0]);
            lacc[1] = MFMA16(ones, pfrag[1][tb], lacc[1]);
        }
        __builtin_amdgcn_s_barrier();
    }

    // ---- epilogue: normalize lane-locally, store f32x4 per (f, h-quad) ----
    #pragma unroll
    for (int fs = 0; fs < 2; ++fs) {
        const float inv = 1.0f / lacc[fs][0];
        const int f = f0 + w*32 + fs*16 + l15;
        float* orow = &out[((size_t)(b*S_DIM + f) << 10) + (n << 6) + 4*g];
        #pragma unroll
        for (int hb = 0; hb < 4; ++hb) {
            f32x4 v = o2[fs][hb] * inv;
            *(f32x4*)&orow[hb*16] = v;
        }
    }
}

extern "C" void kernel_launch(void* const* d_in, const int* in_sizes, int n_in,
                              void* d_out, int out_size, void* d_ws, size_t ws_size,
                              hipStream_t stream)
{
    const float* from = (const float*)d_in[0];
    const float* to   = (const float*)d_in[1];
    const int*   mask = (const int*)d_in[2];
    const float* wq   = (const float*)d_in[3];
    const float* bq   = (const float*)d_in[4];
    const float* wk   = (const float*)d_in[5];
    const float* bk   = (const float*)d_in[6];
    const float* wv   = (const float*)d_in[7];
    const float* bv   = (const float*)d_in[8];
    float* out = (float*)d_out;

    char* p = (char*)d_ws;
    const size_t sz_x   = (size_t)M_DIM * D_DIM * 2;
    const size_t sz_w   = (size_t)NH * D_DIM * 2;
    const size_t sz_qkv = (size_t)B_DIM * N_HEADS * S_DIM * H_DIM * 2;
    short* Fb  = (short*)p;            p += sz_x;
    short* Tbf = (short*)p;            p += sz_x;
    short* Wts = (short*)p;            p += 3 * sz_w;   // Q|K|V stacked
    short* Qw  = (short*)p;            p += sz_qkv;
    short* Kw  = (short*)p;            p += sz_qkv;
    short* Vw  = (short*)p;            p += sz_qkv;
    unsigned long long* mpk = (unsigned long long*)p;

    cvt_bf16_2<<<(2 * M_DIM * D_DIM / 4) / 256, 256, 0, stream>>>(from, to, Fb, Tbf);

    dim3 wg(16, 16, 3);
    wtrans3<<<wg, 256, 0, stream>>>(wq, wk, wv, Wts);

    maskpack<<<1024, 256, 0, stream>>>(mask, mpk, B_DIM * S_DIM * (S_DIM / 64));

    dim3 pg(M_DIM / 128, 24);
    proj_mfma<<<pg, 256, 0, stream>>>(Fb, Tbf, Wts, bq, bk, bv, Qw, Kw, Vw);

    dim3 ag(S_DIM / 128, N_HEADS, B_DIM);
    attn_mfma<<<ag, 256, 0, stream>>>(Qw, Kw, Vw, mpk, out);
}

// Round 7
// 152.351 us; speedup vs baseline: 7.4890x; 1.0235x over previous
//
#include <hip/hip_runtime.h>

#define B_DIM   2
#define S_DIM   2048
#define D_DIM   1024
#define N_HEADS 16
#define H_DIM   64
#define NH      1024
#define M_DIM   4096   // B * S

typedef short bf16x8 __attribute__((ext_vector_type(8)));
typedef short bf16x4 __attribute__((ext_vector_type(4)));
typedef float f32x4  __attribute__((ext_vector_type(4)));

// exact power-of-two scale folded into Q (1/sqrt(64)); exp stays natural
#define QSCALE 0.125f

__device__ __forceinline__ short f2bf(float x) {
    unsigned u = __float_as_uint(x);
    u = (u + 0x7fffu + ((u >> 16) & 1u)) >> 16;   // RNE
    return (short)u;
}

__device__ __forceinline__ void glds16(const void* g, void* l) {
    __builtin_amdgcn_global_load_lds(
        (const __attribute__((address_space(1))) unsigned int*)g,
        (__attribute__((address_space(3))) unsigned int*)l, 16, 0, 0);
}

#define VMCNT(n) asm volatile("s_waitcnt vmcnt(" #n ")" ::: "memory")

#if __has_builtin(__builtin_amdgcn_mfma_f32_16x16x16bf16_1k)
#define MFMA16(a, b, c) __builtin_amdgcn_mfma_f32_16x16x16bf16_1k(a, b, c, 0, 0, 0)
#else
__device__ __forceinline__ f32x4 mfma16_fb(bf16x4 a, bf16x4 b, f32x4 c) {
    f32x4 d;
    asm volatile("v_mfma_f32_16x16x16_bf16 %0, %2, %3, %1\n\t"
                 "s_nop 7\n\ts_nop 3"
                 : "=v"(d) : "0"(c), "v"(a), "v"(b));
    return d;
}
#define MFMA16(a, b, c) mfma16_fb(a, b, c)
#endif

// ---------------------------------------------------------------------------
// f32 -> bf16 convert, both input tensors in one launch
// ---------------------------------------------------------------------------
__global__ __launch_bounds__(256)
void cvt_bf16_2(const float* __restrict__ a, const float* __restrict__ b,
                short* __restrict__ da, short* __restrict__ db) {
    const int n4 = (M_DIM * D_DIM) / 4;
    int i = blockIdx.x * blockDim.x + threadIdx.x;
    const float* s = (i < n4) ? a : b;
    short* d = (i < n4) ? da : db;
    int j = (i < n4) ? i : i - n4;
    float4 v = ((const float4*)s)[j];
    bf16x4 o;
    o[0] = f2bf(v.x); o[1] = f2bf(v.y); o[2] = f2bf(v.z); o[3] = f2bf(v.w);
    ((bf16x4*)d)[j] = o;
}

// ---------------------------------------------------------------------------
// W [1024 d][1024 nh] f32 -> Wt [1024 nh][1024 d] bf16; z selects wq/wk/wv
// ---------------------------------------------------------------------------
__global__ __launch_bounds__(256)
void wtrans3(const float* __restrict__ wq, const float* __restrict__ wk,
             const float* __restrict__ wv, short* __restrict__ Wt) {
    __shared__ short T[64][66];
    const int z = blockIdx.z;
    const float* W = (z == 0) ? wq : (z == 1) ? wk : wv;
    short* dst = Wt + (size_t)z * NH * D_DIM;
    const int d0 = blockIdx.x * 64, n0 = blockIdx.y * 64;
    const int tid = threadIdx.x;
    {
        const int dr = tid >> 2, nc = (tid & 3) * 16;
        const float* src = &W[(size_t)(d0 + dr) * NH + n0 + nc];
        float vv[16];
        #pragma unroll
        for (int q = 0; q < 4; ++q) {
            float4 v = ((const float4*)src)[q];
            vv[q*4+0] = v.x; vv[q*4+1] = v.y; vv[q*4+2] = v.z; vv[q*4+3] = v.w;
        }
        #pragma unroll
        for (int j = 0; j < 16; ++j) T[nc + j][dr] = f2bf(vv[j]);
    }
    __syncthreads();
    {
        const int nr = tid >> 2, dc = (tid & 3) * 16;
        short o[16];
        #pragma unroll
        for (int j = 0; j < 16; ++j) o[j] = T[nr][dc + j];
        short* dstp = &dst[(size_t)(n0 + nr) * D_DIM + d0 + dc];
        *(bf16x8*)(dstp)     = *(bf16x8*)&o[0];
        *(bf16x8*)(dstp + 8) = *(bf16x8*)&o[8];
    }
}

// ---------------------------------------------------------------------------
// mask int32 [B][F][T] -> packed bits u64 [B][F][T/64]
// ---------------------------------------------------------------------------
__global__ __launch_bounds__(256)
void maskpack(const int* __restrict__ mask, unsigned long long* __restrict__ mp,
              int total) {
    const int lane = threadIdx.x & 63;
    const int wid  = (blockIdx.x * blockDim.x + threadIdx.x) >> 6;
    const int nw   = (gridDim.x * blockDim.x) >> 6;
    for (int idx = wid; idx < total; idx += nw) {
        int m = mask[(size_t)idx * 64 + lane];
        unsigned long long bits = __ballot(m != 0);
        if (lane == 0) mp[idx] = bits;
    }
}

// ---------------------------------------------------------------------------
// Fused QKV projection. Grid (32, 24): y 0-7 = Q, 8-15 = K, 16-23 = V.
// Wt = [3072][1024] bf16 stacked. Q scaled by 0.125 (exact).
// Q/K out: [B][N][S][H] bf16; V out: [B][N][H][S] bf16 (transposed).
// ---------------------------------------------------------------------------
__global__ __launch_bounds__(256)
void proj_mfma(const short* __restrict__ Fb, const short* __restrict__ Tb_,
               const short* __restrict__ Wt,
               const float* __restrict__ bq, const float* __restrict__ bk,
               const float* __restrict__ bv,
               short* __restrict__ Qo, short* __restrict__ Ko,
               short* __restrict__ Vo)
{
    __shared__ short Al[2][4096];
    __shared__ short Bl[2][4096];
    __shared__ short Tt[4][16][20];

    const int tid  = threadIdx.x;
    const int lane = tid & 63, w = tid >> 6;
    const int g = lane >> 4, l15 = lane & 15;
    const int wm = w >> 1, wn = w & 1;
    const int row0 = blockIdx.x * 128;
    const int region = blockIdx.y >> 3;            // 0=Q 1=K 2=V
    const short* X = (region == 0) ? Fb : Tb_;

    const int cl8   = ((lane & 3) ^ ((lane >> 3) & 3)) * 8;
    const size_t aOff0 = (size_t)(w * 32 + (lane >> 2)) * D_DIM + cl8;
    const size_t aOff1 = aOff0 + 16 * D_DIM;
    const short* Abase = X + (size_t)row0 * D_DIM;
    const short* Bbase = Wt + (size_t)blockIdx.y * 128 * D_DIM;

    const int swz3 = (l15 >> 1) & 3;

    f32x4 acc[4][4];
    #pragma unroll
    for (int i = 0; i < 4; ++i)
        #pragma unroll
        for (int j = 0; j < 4; ++j)
            acc[i][j] = (f32x4){0.f, 0.f, 0.f, 0.f};

    glds16(Abase + aOff0, &Al[0][w * 1024]);
    glds16(Abase + aOff1, &Al[0][w * 1024 + 512]);
    glds16(Bbase + aOff0, &Bl[0][w * 1024]);
    glds16(Bbase + aOff1, &Bl[0][w * 1024 + 512]);

    for (int kt = 0; kt < 32; ++kt) {
        const int cur = kt & 1;
        if (kt < 31) {
            const int k1 = (kt + 1) * 32;
            glds16(Abase + k1 + aOff0, &Al[cur ^ 1][w * 1024]);
            glds16(Abase + k1 + aOff1, &Al[cur ^ 1][w * 1024 + 512]);
            glds16(Bbase + k1 + aOff0, &Bl[cur ^ 1][w * 1024]);
            glds16(Bbase + k1 + aOff1, &Bl[cur ^ 1][w * 1024 + 512]);
            VMCNT(4);
        } else {
            VMCNT(0);
        }
        __builtin_amdgcn_s_barrier();
        __builtin_amdgcn_sched_barrier(0);

        bf16x8 af[4], bfr[4];
        #pragma unroll
        for (int mb = 0; mb < 4; ++mb)
            af[mb] = *(const bf16x8*)&Al[cur][(wm*64 + mb*16 + l15)*32 + (g ^ swz3)*8];
        #pragma unroll
        for (int nb = 0; nb < 4; ++nb)
            bfr[nb] = *(const bf16x8*)&Bl[cur][(wn*64 + nb*16 + l15)*32 + (g ^ swz3)*8];
        #pragma unroll
        for (int mb = 0; mb < 4; ++mb)
            #pragma unroll
            for (int nb = 0; nb < 4; ++nb)
                acc[mb][nb] = __builtin_amdgcn_mfma_f32_16x16x32_bf16(
                    af[mb], bfr[nb], acc[mb][nb], 0, 0, 0);
        __builtin_amdgcn_sched_barrier(0);
        __builtin_amdgcn_s_barrier();
    }

    const float* bias = (region == 0) ? bq : (region == 1) ? bk : bv;
    const float scale = (region == 0) ? QSCALE : 1.0f;
    const int colL0 = (blockIdx.y & 7) * 128 + wn * 64;

    if (region < 2) {
        short* Out = (region == 0) ? Qo : Ko;
        #pragma unroll
        for (int mb = 0; mb < 4; ++mb)
            #pragma unroll
            for (int nb = 0; nb < 4; ++nb) {
                const float bvv = bias[colL0 + nb*16 + l15];
                #pragma unroll
                for (int r = 0; r < 4; ++r)
                    Tt[w][4*g + r][l15] = f2bf((acc[mb][nb][r] + bvv) * scale);
                bf16x4 t4 = *(const bf16x4*)&Tt[w][l15][4*g];
                const int sg  = row0 + wm*64 + mb*16 + l15;
                const int bb  = sg >> 11, s = sg & 2047;
                const int cg  = colL0 + nb*16 + 4*g;
                const int n   = cg >> 6, hh = cg & 63;
                *(bf16x4*)&Out[(((size_t)(bb*N_HEADS + n)*S_DIM + s) << 6) + hh] = t4;
            }
    } else {
        #pragma unroll
        for (int mb = 0; mb < 4; ++mb)
            #pragma unroll
            for (int nb = 0; nb < 4; ++nb) {
                const int nhv = colL0 + nb*16 + l15;
                const float bvv = bias[nhv];
                bf16x4 t4;
                #pragma unroll
                for (int r = 0; r < 4; ++r)
                    t4[r] = f2bf(acc[mb][nb][r] + bvv);
                const int s4 = row0 + wm*64 + mb*16 + 4*g;
                const int bb = s4 >> 11, s = s4 & 2047;
                *(bf16x4*)&Vo[((size_t)(bb*NH + nhv) << 11) + s] = t4;
            }
    }
}

// ---------------------------------------------------------------------------
// Flash attention v7: v6 geometry (64 f-rows/block, 1024 blocks, XCD swizzle,
// hoisted LDS offsets) + sched_barrier(0) fences pinning LDS reads inside
// the barrier-protected region (rule #18: s_barrier builtin is not a
// compile-time memory fence; a hoisted ds_read raced staging in r6 -> NaN).
// ---------------------------------------------------------------------------
__global__ __launch_bounds__(256)
void attn_mfma(const short* __restrict__ Qb, const short* __restrict__ Kb,
               const short* __restrict__ Vt,
               const unsigned long long* __restrict__ mp,
               float* __restrict__ out)
{
    __shared__ short Kl[2][4096];   // [buf][t-row * 64 + swizzled chunk]
    __shared__ short Vl[2][4096];   // [buf][h-row * 64 + swizzled chunk]

    const int tid  = threadIdx.x;
    const int lane = tid & 63, w = tid >> 6;
    const int g = lane >> 4, l15 = lane & 15;

    // XCD swizzle: each XCD gets 128 consecutive logical blocks = 4 heads
    const int lin = (blockIdx.x & 7) * 128 + (blockIdx.x >> 3);
    const int f0 = (lin & 31) << 6;
    const int n  = (lin >> 5) & 15;
    const int b  = lin >> 9;

    const short* Qbase = Qb + (size_t)(b*N_HEADS + n) * S_DIM * H_DIM;
    const short* Kbase = Kb + (size_t)(b*N_HEADS + n) * S_DIM * H_DIM;
    const short* Vbase = Vt + (size_t)(b*NH + n*H_DIM) * S_DIM;

    const int frow = f0 + w*16 + l15;        // this lane's f (fragment col)

    bf16x8 qf[2];
    #pragma unroll
    for (int hc = 0; hc < 2; ++hc)
        qf[hc] = *(const bf16x8*)&Qbase[(size_t)frow * H_DIM + hc*32 + 8*g];

    const int rk  = w * 16 + (lane >> 3);
    const int cl8 = ((lane & 7) ^ (lane >> 3)) * 8;
    const size_t kOff0 = (size_t)rk * H_DIM + cl8;
    const size_t kOff1 = kOff0 + 8 * H_DIM;
    const size_t vOff0 = (size_t)rk * S_DIM + cl8;
    const size_t vOff1 = vOff0 + 8 * S_DIM;

    const unsigned long long* mrp = mp + ((size_t)(b*S_DIM + frow) << 5);

    const int swz7 = l15 & 7;
    const bf16x4 ones = {0x3F80, 0x3F80, 0x3F80, 0x3F80};

    int koffA[4], koffB[4], voff[4][4];
    #pragma unroll
    for (int tb = 0; tb < 4; ++tb) {
        koffA[tb] = ((tb*16 + l15)*64 + ((g    ) ^ swz7)*8) * 2;
        koffB[tb] = ((tb*16 + l15)*64 + ((4 + g) ^ swz7)*8) * 2;
        #pragma unroll
        for (int hb = 0; hb < 4; ++hb)
            voff[tb][hb] = ((hb*16 + l15)*64
                            + ((2*tb + (g>>1)) ^ swz7)*8 + (g & 1)*4) * 2;
    }

    f32x4 o2[4];
    f32x4 lacc;
    #pragma unroll
    for (int hb = 0; hb < 4; ++hb) o2[hb] = (f32x4){0.f, 0.f, 0.f, 0.f};
    lacc = (f32x4){0.f, 0.f, 0.f, 0.f};

    glds16(Kbase + kOff0, &Kl[0][w * 1024]);
    glds16(Kbase + kOff1, &Kl[0][w * 1024 + 512]);
    glds16(Vbase + vOff0, &Vl[0][w * 1024]);
    glds16(Vbase + vOff1, &Vl[0][w * 1024 + 512]);

    const char* KlB = (const char*)&Kl[0][0];
    const char* VlB = (const char*)&Vl[0][0];

    for (int tt = 0; tt < 32; ++tt) {
        const int cur = tt & 1;
        const int cb  = cur << 13;           // byte offset of current buffer

        const unsigned long long mk = mrp[tt];
        __builtin_amdgcn_sched_barrier(0);

        if (tt < 31) {
            const int t1 = (tt + 1) * 64;
            glds16(Kbase + (size_t)t1*H_DIM + kOff0, &Kl[cur^1][w*1024]);
            glds16(Kbase + (size_t)t1*H_DIM + kOff1, &Kl[cur^1][w*1024 + 512]);
            glds16(Vbase + t1 + vOff0, &Vl[cur^1][w*1024]);
            glds16(Vbase + t1 + vOff1, &Vl[cur^1][w*1024 + 512]);
            VMCNT(4);
        } else {
            VMCNT(0);
        }
        __builtin_amdgcn_s_barrier();
        __builtin_amdgcn_sched_barrier(0);   // pin ds_reads AFTER the barrier

        // ---- QK^T + mask-zero + exp -> P fragments (registers only) ----
        bf16x4 pfrag[4];   // [tb]: P[t=16tb+4g+r][f=l15]
        #pragma unroll
        for (int tb = 0; tb < 4; ++tb) {
            bf16x8 kf0 = *(const bf16x8*)(KlB + cb + koffA[tb]);
            bf16x8 kf1 = *(const bf16x8*)(KlB + cb + koffB[tb]);
            const f32x4 z = (f32x4){0.f, 0.f, 0.f, 0.f};
            f32x4 sv = __builtin_amdgcn_mfma_f32_16x16x32_bf16(kf0, qf[0], z, 0, 0, 0);
            sv = __builtin_amdgcn_mfma_f32_16x16x32_bf16(kf1, qf[1], sv, 0, 0, 0);
            const unsigned mb_ = (unsigned)(mk >> (tb*16 + 4*g));
            float p0 = (mb_ & 1u) ? __expf(sv[0]) : 0.f;
            float p1 = (mb_ & 2u) ? __expf(sv[1]) : 0.f;
            float p2 = (mb_ & 4u) ? __expf(sv[2]) : 0.f;
            float p3 = (mb_ & 8u) ? __expf(sv[3]) : 0.f;
            unsigned u0, u1;
            asm("v_cvt_pk_bf16_f32 %0, %1, %2" : "=v"(u0) : "v"(p0), "v"(p1));
            asm("v_cvt_pk_bf16_f32 %0, %1, %2" : "=v"(u1) : "v"(p2), "v"(p3));
            union { unsigned u[2]; bf16x4 v; } pk;
            pk.u[0] = u0;
            pk.u[1] = u1;
            pfrag[tb] = pk.v;
        }

        // ---- PV: O^T[h][f] += V^T-frag x P-frag; denominator via ones ----
        #pragma unroll
        for (int tb = 0; tb < 4; ++tb) {
            #pragma unroll
            for (int hb = 0; hb < 4; ++hb) {
                bf16x4 va = *(const bf16x4*)(VlB + cb + voff[tb][hb]);
                o2[hb] = MFMA16(va, pfrag[tb], o2[hb]);
            }
            lacc = MFMA16(ones, pfrag[tb], lacc);
        }
        __builtin_amdgcn_sched_barrier(0);   // pin reads BEFORE exit barrier
        __builtin_amdgcn_s_barrier();
    }

    // ---- epilogue: normalize lane-locally, store f32x4 per (f, h-quad) ----
    {
        const float inv = 1.0f / lacc[0];
        float* orow = &out[((size_t)(b*S_DIM + frow) << 10) + (n << 6) + 4*g];
        #pragma unroll
        for (int hb = 0; hb < 4; ++hb) {
            f32x4 v = o2[hb] * inv;
            *(f32x4*)&orow[hb*16] = v;
        }
    }
}

extern "C" void kernel_launch(void* const* d_in, const int* in_sizes, int n_in,
                              void* d_out, int out_size, void* d_ws, size_t ws_size,
                              hipStream_t stream)
{
    const float* from = (const float*)d_in[0];
    const float* to   = (const float*)d_in[1];
    const int*   mask = (const int*)d_in[2];
    const float* wq   = (const float*)d_in[3];
    const float* bq   = (const float*)d_in[4];
    const float* wk   = (const float*)d_in[5];
    const float* bk   = (const float*)d_in[6];
    const float* wv   = (const float*)d_in[7];
    const float* bv   = (const float*)d_in[8];
    float* out = (float*)d_out;

    char* p = (char*)d_ws;
    const size_t sz_x   = (size_t)M_DIM * D_DIM * 2;
    const size_t sz_w   = (size_t)NH * D_DIM * 2;
    const size_t sz_qkv = (size_t)B_DIM * N_HEADS * S_DIM * H_DIM * 2;
    short* Fb  = (short*)p;            p += sz_x;
    short* Tbf = (short*)p;            p += sz_x;
    short* Wts = (short*)p;            p += 3 * sz_w;   // Q|K|V stacked
    short* Qw  = (short*)p;            p += sz_qkv;
    short* Kw  = (short*)p;            p += sz_qkv;
    short* Vw  = (short*)p;            p += sz_qkv;
    unsigned long long* mpk = (unsigned long long*)p;

    cvt_bf16_2<<<(2 * M_DIM * D_DIM / 4) / 256, 256, 0, stream>>>(from, to, Fb, Tbf);

    dim3 wg(16, 16, 3);
    wtrans3<<<wg, 256, 0, stream>>>(wq, wk, wv, Wts);

    maskpack<<<1024, 256, 0, stream>>>(mask, mpk, B_DIM * S_DIM * (S_DIM / 64));

    dim3 pg(M_DIM / 128, 24);
    proj_mfma<<<pg, 256, 0, stream>>>(Fb, Tbf, Wts, bq, bk, bv, Qw, Kw, Vw);

    attn_mfma<<<1024, 256, 0, stream>>>(Qw, Kw, Vw, mpk, out);
}